// Round 3
// baseline (1880.287 us; speedup 1.0000x reference)
//
#include <hip/hip_runtime.h>
#include <stdint.h>
#include <stddef.h>

typedef _Float16 f16;
typedef f16 f16x8 __attribute__((ext_vector_type(8)));
typedef float f32x4 __attribute__((ext_vector_type(4)));

#define STRIDE 616          // LDS row stride (f16): 1232 B; 308 dwords, 308%32=20 -> spreads banks
#define TROWS  32           // R6: 32-row tile -> 78.8 KB LDS -> 2 blocks/CU
#define BATCH  131072

// Per-layer dims: (o, k); kpad = align32(k); opad = align128(o) = T*8*16
static constexpr int  LO[10]  = {600,600,160,600,600,379,40,40,40,2};
static constexpr int  LK[10]  = {379,600,600,80,600,600,160,40,40,40};
static constexpr int  LKP[10] = {384,608,608,96,608,608,160,64,64,64};
static constexpr long WOFF[11] = {0,245760,634880,790528,851968,1241088,1474560,1495040,1503232,1511424,1519616};
#define WTOTAL 1519616      // f16 elems (~2.9 MB in d_ws)

// ---------------------------------------------------------------------------
// Harness delivers integer inputs as int32. int32 [o][k] -> f16 padded
// [opad][kpad], exact integer values; scale/bias applied in fp32 epilogue.
// ---------------------------------------------------------------------------
struct ConvArgs { const int* w[10]; f16* dst; };

__global__ __launch_bounds__(256) void convert_weights(ConvArgs a) {
  long e8 = ((long)blockIdx.x * 256 + threadIdx.x) * 8;
#pragma unroll
  for (int l = 0; l < 10; ++l) {
    if (e8 >= WOFF[l] && e8 < WOFF[l + 1]) {
      int local = (int)(e8 - WOFF[l]);
      int o  = local / LKP[l];
      int k0 = local - o * LKP[l];
      const int* w = a.w[l];
      f16 v8[8];
#pragma unroll
      for (int j = 0; j < 8; ++j) {
        int k = k0 + j;
        int iv = (o < LO[l] && k < LK[l]) ? w[o * LK[l] + k] : 0;
        v8[j] = (f16)(float)iv;
      }
      *(f16x8*)(a.dst + e8) = *(const f16x8*)v8;
    }
  }
}

// ---------------------------------------------------------------------------
// Activations. tanh/sigmoid use v_rcp_f32 instead of the full IEEE divide
// sequence -- ~1ulp rcp is far below the f16 activation-storage noise floor.
// ---------------------------------------------------------------------------
__device__ __forceinline__ float act_elu(float x)  { return x > 0.f ? x : __expf(x) - 1.f; }
__device__ __forceinline__ float act_tanh(float x) {
  float s = __expf(-2.f * fabsf(x));
  float t = (1.f - s) * __builtin_amdgcn_rcpf(1.f + s);
  return x >= 0.f ? t : -t;
}
__device__ __forceinline__ float act_softplus(float x) {
  return fmaxf(x, 0.f) + __logf(1.f + __expf(-fabsf(x)));
}
__device__ __forceinline__ float act_sigmoid(float x) {
  return __builtin_amdgcn_rcpf(1.f + __expf(-x));
}

// ---------------------------------------------------------------------------
// One fused linear layer on a 32-row LDS tile, 8 waves (R6).
//
// R6 theory: R5's 16-wave block hit a 64-VGPR cap (backend treated
// __launch_bounds__ arg2 as min-BLOCKS/CU: 4 blocks x 16 waves -> 32-wave
// clamp -> 64 VGPR) which spilled the k-pipeline (FETCH +129MB / WRITE
// +263MB scratch traffic, MfmaUtil 14.7->12.2). Fix: get 4 waves/SIMD from
// TWO co-resident blocks (32-row tile -> 78.8KB LDS x2 = 157.7KB <= 160KB)
// instead of a fatter block. Per-wave: acc[T][2] + b0/b1[T] + a0/a1[2]
// ~ 110 VGPR, fits the 128 cap of 16 waves/CU. Co-resident blocks are
// barrier-independent: when one drains at __syncthreads the other keeps
// the MFMA/LDS/L2 pipes fed.
//
// MFMA 16x16x32 f16: A[m=lane&15][k=(lane>>4)*8+j], B[k][n]=W[n][k] (8
// contiguous k per lane), C/D col=lane&15 row=(lane>>4)*4+i (verified R3).
// ACT: 1=elu->LDS, 2=tanh->LDS, 5=L2 (mu raw / softplus sigma -> LDS+global),
//      6=sigmoid(softplus)->global, 7=softplus->global
// ---------------------------------------------------------------------------
template <int ACT, int T, int KP>
__device__ __forceinline__ void gemm_layer(
    const f16* __restrict__ Wf, const float* __restrict__ sv, const float* __restrict__ bv,
    int o_real,
    const f16* lin, f16* lout, int out_cols,
    float* __restrict__ g0, float* __restrict__ g1, long row0, int gw,
    int wn, int lrow, int lq) {
  f32x4 acc[T][2];
#pragma unroll
  for (int t = 0; t < T; ++t)
#pragma unroll
    for (int m = 0; m < 2; ++m) acc[t][m] = (f32x4){0.f, 0.f, 0.f, 0.f};

  const f16* ap = lin + lrow * STRIDE + lq * 8;
  const f16* bp[T];
#pragma unroll
  for (int t = 0; t < T; ++t) {
    int n = (wn + 8 * t) * 16 + lrow;
    bp[t] = Wf + (size_t)n * KP + lq * 8;
  }

  constexpr int NK = KP / 32;  // all layers have NK >= 2
  f16x8 a0[2], a1[2], b0[T], b1[T];

  // prologue: k-step 0 into buffer 0
#pragma unroll
  for (int m = 0; m < 2; ++m) a0[m] = *(const f16x8*)(ap + m * 16 * STRIDE);
#pragma unroll
  for (int t = 0; t < T; ++t) b0[t] = *(const f16x8*)(bp[t]);

#pragma unroll
  for (int kk = 0; kk < NK; ++kk) {
    const int kn = (kk + 1) * 32;
    if ((kk & 1) == 0) {
      if (kk + 1 < NK) {
#pragma unroll
        for (int m = 0; m < 2; ++m) a1[m] = *(const f16x8*)(ap + m * 16 * STRIDE + kn);
#pragma unroll
        for (int t = 0; t < T; ++t) b1[t] = *(const f16x8*)(bp[t] + kn);
      }
#pragma unroll
      for (int t = 0; t < T; ++t)
#pragma unroll
        for (int m = 0; m < 2; ++m)
          acc[t][m] = __builtin_amdgcn_mfma_f32_16x16x32_f16(a0[m], b0[t], acc[t][m], 0, 0, 0);
    } else {
      if (kk + 1 < NK) {
#pragma unroll
        for (int m = 0; m < 2; ++m) a0[m] = *(const f16x8*)(ap + m * 16 * STRIDE + kn);
#pragma unroll
        for (int t = 0; t < T; ++t) b0[t] = *(const f16x8*)(bp[t] + kn);
      }
#pragma unroll
      for (int t = 0; t < T; ++t)
#pragma unroll
        for (int m = 0; m < 2; ++m)
          acc[t][m] = __builtin_amdgcn_mfma_f32_16x16x32_f16(a1[m], b1[t], acc[t][m], 0, 0, 0);
    }
  }

#pragma unroll
  for (int t = 0; t < T; ++t) {
    int n = (wn + 8 * t) * 16 + lrow;
    bool nv = n < o_real;
    float sc = nv ? sv[n] * (1.f / 127.f) : 0.f;
    float bb = nv ? bv[n] : 0.f;
#pragma unroll
    for (int m = 0; m < 2; ++m) {
#pragma unroll
      for (int i = 0; i < 4; ++i) {
        int row = m * 16 + lq * 4 + i;
        float v = acc[t][m][i] * sc + bb;
        if (ACT == 1 || ACT == 2) {
          float r = (ACT == 1) ? act_elu(v) : act_tanh(v);
          if (n < out_cols) lout[row * STRIDE + n] = nv ? (f16)r : (f16)0.f;
        } else if (ACT == 5) {
          if (n < 80) {
            g0[(row0 + row) * 80 + n] = v;
            lout[row * STRIDE + n] = (f16)v;
          } else if (n < 160) {
            float sp = act_softplus(v);
            g1[(row0 + row) * 80 + (n - 80)] = sp;
            lout[row * STRIDE + n] = (f16)sp;
          }
        } else if (ACT == 6) {
          if (nv) g0[(row0 + row) * gw + n] = act_sigmoid(act_softplus(v));
        } else if (ACT == 7) {
          if (nv) g0[(row0 + row) * gw + n] = act_softplus(v);
        }
      }
    }
  }
  __syncthreads();
}

// ---------------------------------------------------------------------------
struct FusedArgs {
  const float* x; const float* eps;
  const f16* wf[10];
  const float* s[10]; const float* b[10];
  float* mlp; float* vae; float* mu; float* sig;
};

__global__ __launch_bounds__(512, 2) void fused_kernel(FusedArgs A) {
  extern __shared__ char smem[];
  f16* bufA = (f16*)smem;
  f16* bufB = bufA + TROWS * STRIDE;
  const int tid  = threadIdx.x;
  const int lane = tid & 63;
  const int wn   = tid >> 6;       // 0..7, N-group
  const int lrow = lane & 15, lq = lane >> 4;
  const long row0 = (long)blockIdx.x * TROWS;

#define GLAYER(ACTV, T, L, IN, OUT, OUTC, G0, G1, GW) \
  gemm_layer<ACTV, T, LKP[L]>(A.wf[L], A.s[L], A.b[L], LO[L], \
      IN, OUT, OUTC, G0, G1, row0, GW, wn, lrow, lq)

  // stage x (fp32 [B,379]) -> bufA f16, cols 379..383 zeroed
  for (int idx = tid; idx < TROWS * 384; idx += 512) {
    int r = idx / 384, c = idx - r * 384;
    float v = (c < 379) ? A.x[(row0 + r) * 379 + c] : 0.f;
    bufA[r * STRIDE + c] = (f16)v;
  }
  __syncthreads();

  // encoder
  GLAYER(1, 5, 0, bufA, bufB, 608, nullptr, nullptr, 0);
  GLAYER(2, 5, 1, bufB, bufA, 608, nullptr, nullptr, 0);
  GLAYER(5, 2, 2, bufA, bufB, 160, A.mu, A.sig, 0);

  // z = fp16(mu + sigma*eps) -> bufA cols [0,96)
  for (int idx = tid; idx < TROWS * 96; idx += 512) {
    int r = idx / 96, c = idx - r * 96;
    float zv = 0.f;
    if (c < 80) {
      float muv = (float)bufB[r * STRIDE + c];
      float sgv = (float)bufB[r * STRIDE + 80 + c];
      zv = muv + sgv * A.eps[(row0 + r) * 80 + c];
    }
    bufA[r * STRIDE + c] = (f16)zv;
  }
  __syncthreads();

  // m-chain (input bufB cols [0,160) = [mu | softplus(sigma)])
  GLAYER(2, 1, 6, bufB, bufA + 128, 64, nullptr, nullptr, 0);
  GLAYER(1, 1, 7, bufA + 128, bufB, 64, nullptr, nullptr, 0);
  GLAYER(1, 1, 8, bufB, bufA + 192, 64, nullptr, nullptr, 0);
  GLAYER(7, 1, 9, bufA + 192, nullptr, 0, A.mlp, nullptr, 2);

  // d-chain (input z = bufA cols [0,96))
  GLAYER(2, 5, 3, bufA, bufB, 608, nullptr, nullptr, 0);
  GLAYER(1, 5, 4, bufB, bufA, 608, nullptr, nullptr, 0);
  GLAYER(6, 3, 5, bufA, nullptr, 0, A.vae, nullptr, 379);
#undef GLAYER
}

// ---------------------------------------------------------------------------
extern "C" void kernel_launch(void* const* d_in, const int* in_sizes, int n_in,
                              void* d_out, int out_size, void* d_ws, size_t ws_size,
                              hipStream_t stream) {
  (void)in_sizes; (void)n_in; (void)out_size; (void)ws_size;

  f16* wf = (f16*)d_ws;

  ConvArgs ca;
  for (int l = 0; l < 10; ++l) ca.w[l] = (const int*)d_in[2 + 3 * l];
  ca.dst = wf;
  hipLaunchKernelGGL(convert_weights, dim3(742), dim3(256), 0, stream, ca);  // 742*256*8 == WTOTAL

  FusedArgs fa;
  fa.x   = (const float*)d_in[0];
  fa.eps = (const float*)d_in[1];
  for (int l = 0; l < 10; ++l) {
    fa.wf[l] = wf + WOFF[l];
    fa.s[l]  = (const float*)d_in[3 + 3 * l];
    fa.b[l]  = (const float*)d_in[4 + 3 * l];
  }
  float* out = (float*)d_out;
  fa.mlp = out;                                   // [B,2]
  fa.vae = out + (long)BATCH * 2;                 // [B,379]
  fa.mu  = out + (long)BATCH * (2 + 379);         // [B,80]
  fa.sig = out + (long)BATCH * (2 + 379 + 80);    // [B,80]

  const int lds_bytes = 2 * TROWS * STRIDE * 2;   // 78848 B -> 2 blocks/CU
  hipFuncSetAttribute(reinterpret_cast<const void*>(fused_kernel),
                      hipFuncAttributeMaxDynamicSharedMemorySize, lds_bytes);
  hipLaunchKernelGGL(fused_kernel, dim3(BATCH / TROWS), dim3(512), lds_bytes, stream, fa);
}

// Round 4
// 1774.730 us; speedup vs baseline: 1.0595x; 1.0595x over previous
//
#include <hip/hip_runtime.h>
#include <stdint.h>
#include <stddef.h>

typedef _Float16 f16;
typedef f16 f16x8 __attribute__((ext_vector_type(8)));
typedef float f32x4 __attribute__((ext_vector_type(4)));

#define STRIDE 616          // LDS row stride (f16): 1232 B; 308 dwords, 308%32=20 -> spreads banks
#define TROWS  48           // R7: 48-row tile, SINGLE in-place buffer: 48*616*2 = 59136 B <= 64 KiB
#define BATCH  131072
#define NBLK   ((BATCH + TROWS - 1) / TROWS)   // 2731, last block has 32 valid rows

// Per-layer dims: (o, k); kpad = align32(k); opad = 8*T*16
static constexpr int  LO[10]  = {600,600,160,600,600,379,40,40,40,2};
static constexpr int  LK[10]  = {379,600,600,80,600,600,160,40,40,40};
static constexpr int  LKP[10] = {384,608,608,96,608,608,160,64,64,64};
static constexpr long WOFF[11] = {0,245760,634880,790528,851968,1241088,1474560,1495040,1503232,1511424,1519616};
#define WTOTAL 1519616      // f16 elems (~2.9 MB in d_ws)

// ---------------------------------------------------------------------------
// int32 [o][k] -> f16 padded [opad][kpad], exact integer values.
// ---------------------------------------------------------------------------
struct ConvArgs { const int* w[10]; f16* dst; };

__global__ __launch_bounds__(256) void convert_weights(ConvArgs a) {
  long e8 = ((long)blockIdx.x * 256 + threadIdx.x) * 8;
#pragma unroll
  for (int l = 0; l < 10; ++l) {
    if (e8 >= WOFF[l] && e8 < WOFF[l + 1]) {
      int local = (int)(e8 - WOFF[l]);
      int o  = local / LKP[l];
      int k0 = local - o * LKP[l];
      const int* w = a.w[l];
      f16 v8[8];
#pragma unroll
      for (int j = 0; j < 8; ++j) {
        int k = k0 + j;
        int iv = (o < LO[l] && k < LK[l]) ? w[o * LK[l] + k] : 0;
        v8[j] = (f16)(float)iv;
      }
      *(f16x8*)(a.dst + e8) = *(const f16x8*)v8;
    }
  }
}

// ---------------------------------------------------------------------------
__device__ __forceinline__ float act_elu(float x)  { return x > 0.f ? x : __expf(x) - 1.f; }
__device__ __forceinline__ float act_tanh(float x) {
  float s = __expf(-2.f * fabsf(x));
  float t = (1.f - s) * __builtin_amdgcn_rcpf(1.f + s);
  return x >= 0.f ? t : -t;
}
__device__ __forceinline__ float act_softplus(float x) {
  return fmaxf(x, 0.f) + __logf(1.f + __expf(-fabsf(x)));
}
__device__ __forceinline__ float act_sigmoid(float x) {
  return __builtin_amdgcn_rcpf(1.f + __expf(-x));
}

// ---------------------------------------------------------------------------
// R7: one fused linear layer, IN-PLACE on a single 48-row LDS buffer.
//
// Evidence trail: R4 (64-row, dbuf, 157.7KB, 1 blk/CU, 2 waves/SIMD) = 1145us,
// 65% issue-stall, no pipe >21%. R5 (1024thr): launch_bounds arg2 = min
// BLOCKS/CU on this toolchain -> 64-VGPR clamp -> spill regression. R6
// (32-row dbuf, 78.8KB): VGPR 76 yet STILL 1 blk/CU -> effective multi-block
// LDS budget < 157.7KB (reservation/granule), and halved per-wave intensity
// regressed to 1570us. Conclusion: need LDS <= ~64KB/block for 2 blocks/CU
// (16 waves/CU is the VGPR-side cap at <=128 VGPR) while KEEPING >=3 M-tiles
// per wave. In-place single buffer does it: barrier between k-loop (all
// reads) and epilogue (writes) makes read/write overlap safe; ping-pong
// buffer was pure LDS waste.
//
// MFMA 16x16x32 f16: A[m=lane&15][k=(lane>>4)*8+j], B[k][n]=W[n][k] (8
// contiguous k per lane), C/D col=lane&15 row=(lane>>4)*4+i (verified R3).
// ACT: 1=elu->LDS, 2=tanh->LDS, 5=L2 (mu raw / softplus sigma -> LDS+global),
//      6=sigmoid(softplus)->global, 7=softplus->global
// LDSW(ACT in {1,2,5}): sync before epilogue (in-place safety) + sync after.
// ---------------------------------------------------------------------------
template <int ACT, int T, int KP>
__device__ __forceinline__ void gemm_layer(
    const f16* __restrict__ Wf, const float* __restrict__ sv, const float* __restrict__ bv,
    int o_real,
    const f16* lin, f16* lout, int out_cols,
    float* __restrict__ g0, float* __restrict__ g1, long row0, int gw,
    int wn, int lrow, int lq) {
  constexpr int M = TROWS / 16;            // 3 M-tiles per wave
  constexpr bool LDSW = (ACT == 1 || ACT == 2 || ACT == 5);

  f32x4 acc[T][M];
#pragma unroll
  for (int t = 0; t < T; ++t)
#pragma unroll
    for (int m = 0; m < M; ++m) acc[t][m] = (f32x4){0.f, 0.f, 0.f, 0.f};

  const f16* ap = lin + lrow * STRIDE + lq * 8;
  const f16* bp[T];
#pragma unroll
  for (int t = 0; t < T; ++t) {
    int n = (wn + 8 * t) * 16 + lrow;
    bp[t] = Wf + (size_t)n * KP + lq * 8;
  }

  constexpr int NK = KP / 32;  // all layers have NK >= 2
  f16x8 a0[M], a1[M], b0[T], b1[T];

  // prologue: k-step 0 into buffer 0
#pragma unroll
  for (int m = 0; m < M; ++m) a0[m] = *(const f16x8*)(ap + m * 16 * STRIDE);
#pragma unroll
  for (int t = 0; t < T; ++t) b0[t] = *(const f16x8*)(bp[t]);

#pragma unroll
  for (int kk = 0; kk < NK; ++kk) {
    const int kn = (kk + 1) * 32;
    if ((kk & 1) == 0) {
      if (kk + 1 < NK) {
#pragma unroll
        for (int m = 0; m < M; ++m) a1[m] = *(const f16x8*)(ap + m * 16 * STRIDE + kn);
#pragma unroll
        for (int t = 0; t < T; ++t) b1[t] = *(const f16x8*)(bp[t] + kn);
      }
#pragma unroll
      for (int t = 0; t < T; ++t)
#pragma unroll
        for (int m = 0; m < M; ++m)
          acc[t][m] = __builtin_amdgcn_mfma_f32_16x16x32_f16(a0[m], b0[t], acc[t][m], 0, 0, 0);
    } else {
      if (kk + 1 < NK) {
#pragma unroll
        for (int m = 0; m < M; ++m) a0[m] = *(const f16x8*)(ap + m * 16 * STRIDE + kn);
#pragma unroll
        for (int t = 0; t < T; ++t) b0[t] = *(const f16x8*)(bp[t] + kn);
      }
#pragma unroll
      for (int t = 0; t < T; ++t)
#pragma unroll
        for (int m = 0; m < M; ++m)
          acc[t][m] = __builtin_amdgcn_mfma_f32_16x16x32_f16(a1[m], b1[t], acc[t][m], 0, 0, 0);
    }
  }

  if (LDSW) __syncthreads();   // in-place: all reads of lin complete before writes

#pragma unroll
  for (int t = 0; t < T; ++t) {
    int n = (wn + 8 * t) * 16 + lrow;
    bool nv = n < o_real;
    float sc = nv ? sv[n] * (1.f / 127.f) : 0.f;
    float bb = nv ? bv[n] : 0.f;
#pragma unroll
    for (int m = 0; m < M; ++m) {
#pragma unroll
      for (int i = 0; i < 4; ++i) {
        int row = m * 16 + lq * 4 + i;
        bool rv = (row0 + row) < BATCH;     // partial last block guard (global only)
        float v = acc[t][m][i] * sc + bb;
        if (ACT == 1 || ACT == 2) {
          float r = (ACT == 1) ? act_elu(v) : act_tanh(v);
          if (n < out_cols) lout[row * STRIDE + n] = nv ? (f16)r : (f16)0.f;
        } else if (ACT == 5) {
          if (n < 80) {
            if (rv) g0[(row0 + row) * 80 + n] = v;
            lout[row * STRIDE + n] = (f16)v;
          } else if (n < 160) {
            float sp = act_softplus(v);
            if (rv) g1[(row0 + row) * 80 + (n - 80)] = sp;
            lout[row * STRIDE + n] = (f16)sp;
          }
        } else if (ACT == 6) {
          if (nv && rv) g0[(row0 + row) * gw + n] = act_sigmoid(act_softplus(v));
        } else if (ACT == 7) {
          if (nv && rv) g0[(row0 + row) * gw + n] = act_softplus(v);
        }
      }
    }
  }
  if (LDSW) __syncthreads();
}

// ---------------------------------------------------------------------------
struct FusedArgs {
  const float* x; const float* eps;
  const f16* wf[10];
  const float* s[10]; const float* b[10];
  float* mlp; float* vae; float* mu; float* sig;
};

// Single-buffer column map (all offsets into one 48x616 f16 tile):
//   x[0,384) -> L0 -> [0,608) -> L1 -> [0,608) -> L2 -> [mu|sp][0,160)
//   L6 [0,160)->[160,224); L7 ->[224,288); L8 ->[288,352); L9 ->global
//   z -> [352,448);  L3 [352,448)->[0,608); L4 ->[0,608); L5 ->global
__global__ __launch_bounds__(512, 2) void fused_kernel(FusedArgs A) {
  extern __shared__ char smem[];
  f16* buf = (f16*)smem;
  const int tid  = threadIdx.x;
  const int lane = tid & 63;
  const int wn   = tid >> 6;       // 0..7, N-group
  const int lrow = lane & 15, lq = lane >> 4;
  const long row0 = (long)blockIdx.x * TROWS;

#define GLAYER(ACTV, T, L, IN, OUT, OUTC, G0, G1, GW) \
  gemm_layer<ACTV, T, LKP[L]>(A.wf[L], A.s[L], A.b[L], LO[L], \
      IN, OUT, OUTC, G0, G1, row0, GW, wn, lrow, lq)

  // stage x (fp32 [B,379]) -> buf f16 [0,384), cols 379..383 zeroed
  for (int idx = tid; idx < TROWS * 384; idx += 512) {
    int r = idx / 384, c = idx - r * 384;
    float v = (c < 379 && (row0 + r) < BATCH) ? A.x[(row0 + r) * 379 + c] : 0.f;
    buf[r * STRIDE + c] = (f16)v;
  }
  __syncthreads();

  // encoder
  GLAYER(1, 5, 0, buf, buf, 608, nullptr, nullptr, 0);
  GLAYER(2, 5, 1, buf, buf, 608, nullptr, nullptr, 0);
  GLAYER(5, 2, 2, buf, buf, 160, A.mu, A.sig, 0);

  // m-chain (input [0,160) = [mu | softplus(sigma)])
  GLAYER(2, 1, 6, buf, buf + 160, 64, nullptr, nullptr, 0);
  GLAYER(1, 1, 7, buf + 160, buf + 224, 64, nullptr, nullptr, 0);
  GLAYER(1, 1, 8, buf + 224, buf + 288, 64, nullptr, nullptr, 0);
  GLAYER(7, 1, 9, buf + 288, nullptr, 0, A.mlp, nullptr, 2);  // global only, no barrier

  // z = fp16(mu + sigma*eps) -> [352,448)  (mu/sp still live at [0,160);
  // z region disjoint from L9's input [288,352) so no barrier needed before)
  for (int idx = tid; idx < TROWS * 96; idx += 512) {
    int r = idx / 96, c = idx - r * 96;
    float zv = 0.f;
    if (c < 80 && (row0 + r) < BATCH) {
      float muv = (float)buf[r * STRIDE + c];
      float sgv = (float)buf[r * STRIDE + 80 + c];
      zv = muv + sgv * A.eps[(row0 + r) * 80 + c];
    }
    buf[r * STRIDE + 352 + c] = (f16)zv;
  }
  __syncthreads();

  // d-chain (input z = [352,448))
  GLAYER(2, 5, 3, buf + 352, buf, 608, nullptr, nullptr, 0);
  GLAYER(1, 5, 4, buf, buf, 608, nullptr, nullptr, 0);
  GLAYER(6, 3, 5, buf, nullptr, 0, A.vae, nullptr, 379);
#undef GLAYER
}

// ---------------------------------------------------------------------------
extern "C" void kernel_launch(void* const* d_in, const int* in_sizes, int n_in,
                              void* d_out, int out_size, void* d_ws, size_t ws_size,
                              hipStream_t stream) {
  (void)in_sizes; (void)n_in; (void)out_size; (void)ws_size;

  f16* wf = (f16*)d_ws;

  ConvArgs ca;
  for (int l = 0; l < 10; ++l) ca.w[l] = (const int*)d_in[2 + 3 * l];
  ca.dst = wf;
  hipLaunchKernelGGL(convert_weights, dim3(742), dim3(256), 0, stream, ca);  // 742*256*8 == WTOTAL

  FusedArgs fa;
  fa.x   = (const float*)d_in[0];
  fa.eps = (const float*)d_in[1];
  for (int l = 0; l < 10; ++l) {
    fa.wf[l] = wf + WOFF[l];
    fa.s[l]  = (const float*)d_in[3 + 3 * l];
    fa.b[l]  = (const float*)d_in[4 + 3 * l];
  }
  float* out = (float*)d_out;
  fa.mlp = out;                                   // [B,2]
  fa.vae = out + (long)BATCH * 2;                 // [B,379]
  fa.mu  = out + (long)BATCH * (2 + 379);         // [B,80]
  fa.sig = out + (long)BATCH * (2 + 379 + 80);    // [B,80]

  const int lds_bytes = TROWS * STRIDE * 2;       // 59136 B -> 2 blocks/CU under any LDS-cap theory
  hipFuncSetAttribute(reinterpret_cast<const void*>(fused_kernel),
                      hipFuncAttributeMaxDynamicSharedMemorySize, lds_bytes);
  hipLaunchKernelGGL(fused_kernel, dim3(NBLK), dim3(512), lds_bytes, stream, fa);
}

// Round 5
// 1665.713 us; speedup vs baseline: 1.1288x; 1.0654x over previous
//
#include <hip/hip_runtime.h>
#include <stdint.h>
#include <stddef.h>

typedef _Float16 f16;
typedef f16 f16x8 __attribute__((ext_vector_type(8)));
typedef float f32x4 __attribute__((ext_vector_type(4)));

#define STRIDE 616          // LDS row stride (f16): 1232 B; 308 dwords, 308%32=20 -> spreads banks
#define BATCH 131072

// Per-layer dims: (o, k); kpad = align32(k); opad = align128(o) = T*8*16
static constexpr int  LO[10]  = {600,600,160,600,600,379,40,40,40,2};
static constexpr int  LK[10]  = {379,600,600,80,600,600,160,40,40,40};
static constexpr int  LKP[10] = {384,608,608,96,608,608,160,64,64,64};
static constexpr long WOFF[11] = {0,245760,634880,790528,851968,1241088,1474560,1495040,1503232,1511424,1519616};
#define WTOTAL 1519616      // f16 elems (~2.9 MB in d_ws)

// ---------------------------------------------------------------------------
// int32 [o][k] -> f16 padded [opad][kpad], exact integer values.
// ---------------------------------------------------------------------------
struct ConvArgs { const int* w[10]; f16* dst; };

__global__ __launch_bounds__(256) void convert_weights(ConvArgs a) {
  long e8 = ((long)blockIdx.x * 256 + threadIdx.x) * 8;
#pragma unroll
  for (int l = 0; l < 10; ++l) {
    if (e8 >= WOFF[l] && e8 < WOFF[l + 1]) {
      int local = (int)(e8 - WOFF[l]);
      int o  = local / LKP[l];
      int k0 = local - o * LKP[l];
      const int* w = a.w[l];
      f16 v8[8];
#pragma unroll
      for (int j = 0; j < 8; ++j) {
        int k = k0 + j;
        int iv = (o < LO[l] && k < LK[l]) ? w[o * LK[l] + k] : 0;
        v8[j] = (f16)(float)iv;
      }
      *(f16x8*)(a.dst + e8) = *(const f16x8*)v8;
    }
  }
}

// ---------------------------------------------------------------------------
__device__ __forceinline__ float act_elu(float x)  { return x > 0.f ? x : __expf(x) - 1.f; }
__device__ __forceinline__ float act_tanh(float x) {
  float s = __expf(-2.f * fabsf(x));
  float t = (1.f - s) * __builtin_amdgcn_rcpf(1.f + s);
  return x >= 0.f ? t : -t;
}
__device__ __forceinline__ float act_softplus(float x) {
  return fmaxf(x, 0.f) + __logf(1.f + __expf(-fabsf(x)));
}
__device__ __forceinline__ float act_sigmoid(float x) {
  return __builtin_amdgcn_rcpf(1.f + __expf(-x));
}

// ---------------------------------------------------------------------------
// One fused linear layer on the 64-row LDS tile, 16 waves.
//
// Evidence trail (R1-R7): 512-thread blocks NEVER co-schedule 2 blocks/CU on
// this config regardless of LDS 59-158KB (R1/R6/R7 all ~24% occupancy);
// 1024-thread block demonstrably gives 16 waves/CU = 48.6% (R5). R5's
// regression was solely the VGPR clamp from __launch_bounds__(1024,4)
// (64 VGPR -> spill: FETCH +129MB, WRITE +263MB scratch). R8: identical
// structure, __launch_bounds__(1024) with NO second arg -> compiler caps at
// 128 VGPR (launchability of 4 waves/SIMD), pipeline live set ~120 fits.
//
// Wave (wn = w&7, wm = w>>3): wn picks N-tiles {wn, wn+8,...} (16 cols),
// wm picks 2-of-4 M-tiles (rows wm*32..+31). Depth-1 k-pipeline: loads for
// k-step kk+1 issue before MFMAs of kk (named double buffers, parity branch,
// all indices compile-time).
//
// MFMA 16x16x32 f16: A[m=lane&15][k=(lane>>4)*8+j], B[k][n]=W[n][k] (8
// contiguous k per lane), C/D col=lane&15 row=(lane>>4)*4+i (verified R3).
// ACT: 1=elu->LDS, 2=tanh->LDS, 5=L2 (mu raw / softplus sigma -> LDS+global),
//      6=sigmoid(softplus)->global, 7=softplus->global
// ---------------------------------------------------------------------------
template <int ACT, int T, int KP>
__device__ __forceinline__ void gemm_layer(
    const f16* __restrict__ Wf, const float* __restrict__ sv, const float* __restrict__ bv,
    int o_real,
    const f16* lin, f16* lout, int out_cols,
    float* __restrict__ g0, float* __restrict__ g1, long row0, int gw,
    int wn, int wm, int lrow, int lq) {
  f32x4 acc[T][2];
#pragma unroll
  for (int t = 0; t < T; ++t)
#pragma unroll
    for (int m = 0; m < 2; ++m) acc[t][m] = (f32x4){0.f, 0.f, 0.f, 0.f};

  const f16* ap = lin + (wm * 32 + lrow) * STRIDE + lq * 8;
  const f16* bp[T];
#pragma unroll
  for (int t = 0; t < T; ++t) {
    int n = (wn + 8 * t) * 16 + lrow;
    bp[t] = Wf + (size_t)n * KP + lq * 8;
  }

  constexpr int NK = KP / 32;  // all layers have NK >= 2
  f16x8 a0[2], a1[2], b0[T], b1[T];

  // prologue: k-step 0 into buffer 0
#pragma unroll
  for (int m = 0; m < 2; ++m) a0[m] = *(const f16x8*)(ap + m * 16 * STRIDE);
#pragma unroll
  for (int t = 0; t < T; ++t) b0[t] = *(const f16x8*)(bp[t]);

#pragma unroll
  for (int kk = 0; kk < NK; ++kk) {
    const int kn = (kk + 1) * 32;
    if ((kk & 1) == 0) {
      if (kk + 1 < NK) {
#pragma unroll
        for (int m = 0; m < 2; ++m) a1[m] = *(const f16x8*)(ap + m * 16 * STRIDE + kn);
#pragma unroll
        for (int t = 0; t < T; ++t) b1[t] = *(const f16x8*)(bp[t] + kn);
      }
#pragma unroll
      for (int t = 0; t < T; ++t)
#pragma unroll
        for (int m = 0; m < 2; ++m)
          acc[t][m] = __builtin_amdgcn_mfma_f32_16x16x32_f16(a0[m], b0[t], acc[t][m], 0, 0, 0);
    } else {
      if (kk + 1 < NK) {
#pragma unroll
        for (int m = 0; m < 2; ++m) a0[m] = *(const f16x8*)(ap + m * 16 * STRIDE + kn);
#pragma unroll
        for (int t = 0; t < T; ++t) b0[t] = *(const f16x8*)(bp[t] + kn);
      }
#pragma unroll
      for (int t = 0; t < T; ++t)
#pragma unroll
        for (int m = 0; m < 2; ++m)
          acc[t][m] = __builtin_amdgcn_mfma_f32_16x16x32_f16(a1[m], b1[t], acc[t][m], 0, 0, 0);
    }
  }

#pragma unroll
  for (int t = 0; t < T; ++t) {
    int n = (wn + 8 * t) * 16 + lrow;
    bool nv = n < o_real;
    float sc = nv ? sv[n] * (1.f / 127.f) : 0.f;
    float bb = nv ? bv[n] : 0.f;
#pragma unroll
    for (int m = 0; m < 2; ++m) {
#pragma unroll
      for (int i = 0; i < 4; ++i) {
        int row = wm * 32 + m * 16 + lq * 4 + i;
        float v = acc[t][m][i] * sc + bb;
        if (ACT == 1 || ACT == 2) {
          float r = (ACT == 1) ? act_elu(v) : act_tanh(v);
          if (n < out_cols) lout[row * STRIDE + n] = nv ? (f16)r : (f16)0.f;
        } else if (ACT == 5) {
          if (n < 80) {
            g0[(row0 + row) * 80 + n] = v;
            lout[row * STRIDE + n] = (f16)v;
          } else if (n < 160) {
            float sp = act_softplus(v);
            g1[(row0 + row) * 80 + (n - 80)] = sp;
            lout[row * STRIDE + n] = (f16)sp;
          }
        } else if (ACT == 6) {
          if (nv) g0[(row0 + row) * gw + n] = act_sigmoid(act_softplus(v));
        } else if (ACT == 7) {
          if (nv) g0[(row0 + row) * gw + n] = act_softplus(v);
        }
      }
    }
  }
  __syncthreads();
}

// ---------------------------------------------------------------------------
struct FusedArgs {
  const float* x; const float* eps;
  const f16* wf[10];
  const float* s[10]; const float* b[10];
  float* mlp; float* vae; float* mu; float* sig;
};

__global__ __launch_bounds__(1024) void fused_kernel(FusedArgs A) {
  extern __shared__ char smem[];
  f16* bufA = (f16*)smem;
  f16* bufB = bufA + 64 * STRIDE;
  const int tid  = threadIdx.x;
  const int lane = tid & 63;
  const int w    = tid >> 6;       // 0..15
  const int wn   = w & 7;          // N-group
  const int wm   = w >> 3;         // M-group (0: rows 0-31, 1: rows 32-63)
  const int lrow = lane & 15, lq = lane >> 4;
  const long row0 = (long)blockIdx.x * 64;

#define GLAYER(ACTV, T, L, IN, OUT, OUTC, G0, G1, GW) \
  gemm_layer<ACTV, T, LKP[L]>(A.wf[L], A.s[L], A.b[L], LO[L], \
      IN, OUT, OUTC, G0, G1, row0, GW, wn, wm, lrow, lq)

  // stage x (fp32 [B,379]) -> bufA f16, cols 379..383 zeroed
  for (int idx = tid; idx < 64 * 384; idx += 1024) {
    int r = idx / 384, c = idx - r * 384;
    float v = (c < 379) ? A.x[(row0 + r) * 379 + c] : 0.f;
    bufA[r * STRIDE + c] = (f16)v;
  }
  __syncthreads();

  // encoder
  GLAYER(1, 5, 0, bufA, bufB, 608, nullptr, nullptr, 0);
  GLAYER(2, 5, 1, bufB, bufA, 608, nullptr, nullptr, 0);
  GLAYER(5, 2, 2, bufA, bufB, 160, A.mu, A.sig, 0);

  // z = fp16(mu + sigma*eps) -> bufA cols [0,96)
  for (int idx = tid; idx < 64 * 96; idx += 1024) {
    int r = idx / 96, c = idx - r * 96;
    float zv = 0.f;
    if (c < 80) {
      float muv = (float)bufB[r * STRIDE + c];
      float sgv = (float)bufB[r * STRIDE + 80 + c];
      zv = muv + sgv * A.eps[(row0 + r) * 80 + c];
    }
    bufA[r * STRIDE + c] = (f16)zv;
  }
  __syncthreads();

  // m-chain (input bufB cols [0,160) = [mu | softplus(sigma)])
  GLAYER(2, 1, 6, bufB, bufA + 128, 64, nullptr, nullptr, 0);
  GLAYER(1, 1, 7, bufA + 128, bufB, 64, nullptr, nullptr, 0);
  GLAYER(1, 1, 8, bufB, bufA + 192, 64, nullptr, nullptr, 0);
  GLAYER(7, 1, 9, bufA + 192, nullptr, 0, A.mlp, nullptr, 2);

  // d-chain (input z = bufA cols [0,96))
  GLAYER(2, 5, 3, bufA, bufB, 608, nullptr, nullptr, 0);
  GLAYER(1, 5, 4, bufB, bufA, 608, nullptr, nullptr, 0);
  GLAYER(6, 3, 5, bufA, nullptr, 0, A.vae, nullptr, 379);
#undef GLAYER
}

// ---------------------------------------------------------------------------
extern "C" void kernel_launch(void* const* d_in, const int* in_sizes, int n_in,
                              void* d_out, int out_size, void* d_ws, size_t ws_size,
                              hipStream_t stream) {
  (void)in_sizes; (void)n_in; (void)out_size; (void)ws_size;

  f16* wf = (f16*)d_ws;

  ConvArgs ca;
  for (int l = 0; l < 10; ++l) ca.w[l] = (const int*)d_in[2 + 3 * l];
  ca.dst = wf;
  hipLaunchKernelGGL(convert_weights, dim3(742), dim3(256), 0, stream, ca);  // 742*256*8 == WTOTAL

  FusedArgs fa;
  fa.x   = (const float*)d_in[0];
  fa.eps = (const float*)d_in[1];
  for (int l = 0; l < 10; ++l) {
    fa.wf[l] = wf + WOFF[l];
    fa.s[l]  = (const float*)d_in[3 + 3 * l];
    fa.b[l]  = (const float*)d_in[4 + 3 * l];
  }
  float* out = (float*)d_out;
  fa.mlp = out;                                   // [B,2]
  fa.vae = out + (long)BATCH * 2;                 // [B,379]
  fa.mu  = out + (long)BATCH * (2 + 379);         // [B,80]
  fa.sig = out + (long)BATCH * (2 + 379 + 80);    // [B,80]

  const int lds_bytes = 2 * 64 * STRIDE * 2;      // 157696 B (1 block/CU, 16 waves)
  hipFuncSetAttribute(reinterpret_cast<const void*>(fused_kernel),
                      hipFuncAttributeMaxDynamicSharedMemorySize, lds_bytes);
  hipLaunchKernelGGL(fused_kernel, dim3(BATCH / 64), dim3(1024), lds_bytes, stream, fa);
}